// Round 10
// baseline (119.253 us; speedup 1.0000x reference)
//
#include <hip/hip_runtime.h>
#include <math.h>

#define D 256
#define B 16
#define L 8
#define N 128

static constexpr float LAMBDA_ASYNC = 0.08f;
static constexpr float LAMBDA_TAU   = 0.12f;

// ws layout (floats) — single rotating buffers (stream is strictly serial):
//   acct[4096]   @ 0      (pre-scaled vin for next layer, [d][b])
//   colsum[256]  @ 4096   (per-d column sums of the CURRENT vin)
//   meta[16]     @ 4352   (meta[0] = fired count of previous layer)
//   fired[128]   @ 4368   (fired flags of current layer)
//   slab[128][4096] @ 4496 (per-node tanh tiles, 2 MB)
// No zeroing needed: every consumed value is rewritten each call; stale slab
// entries are masked by fired=0 in the reduce (poison 0xAA is finite).

#define OFF_COLSUM 4096
#define OFF_META   4352
#define OFF_FIRED  4368
#define OFF_SLAB   4496

// X[b][d] -> xt[d][b]; colsum0[d] = sum_b X[b][d]
__global__ __launch_bounds__(256) void transpose_kernel(
    const float* __restrict__ X, float* __restrict__ xt,
    float* __restrict__ colsum) {
    const int d = threadIdx.x;
    float cs = 0.0f;
    #pragma unroll
    for (int b = 0; b < B; ++b) {
        const float v = X[b * D + d];
        xt[d * 16 + b] = v;
        cs += v;
    }
    colsum[d] = cs;
}

// Grid: 512 blocks = (node n, e-quarter q). Block: 256 thr = 4 waves.
// Wave w owns d-rows [w*64, w*64+64); lane owns e = e0 + lane.
// Hot loop per d-row: 1 coalesced global_load_dword of W (256 B/wave)
// + 4 broadcast ds_read_b128 (vin row) + 16 FMAs. Plain stores, no atomics.
__global__ __launch_bounds__(256) void layer_kernel(
    const float* __restrict__ Wl,         // N*D*D (this layer)
    const float* __restrict__ biasl,      // N*D
    const float* __restrict__ Sl,         // N*D
    const float* __restrict__ rhol,       // N
    const float* __restrict__ boostl,     // N
    const int*  __restrict__ tb,
    const float* __restrict__ vin_src,    // [d][b] PRE-SCALED (xt for l==0)
    const float* __restrict__ colsum,     // [256] colsums of vin_src
    const float* __restrict__ meta_prev,  // fired count of prev layer (null if l==0)
    float* __restrict__ slab,             // [n][4096] tanh tiles
    float* __restrict__ fired_cur,        // N
    float depth, int is_first)
{
    __shared__ float vin[D * 16];        // [d][b], 16 KB
    __shared__ float red[4 * 64 * 17];   // [wave][lane][b] padded, 17.4 KB
    __shared__ float sh[4];

    const int t    = threadIdx.x;
    const int w    = t >> 6;
    const int lane = t & 63;
    const int n    = blockIdx.x >> 2;
    const int e0   = (blockIdx.x & 3) * 64;

    // ---- early W prefetch: rows 0..7 of this wave's d-range (always valid)
    const float* wp = Wl + ((size_t)n * D + (size_t)(w * 64)) * D + (e0 + lane);
    float wa[8], wb[8];
    #pragma unroll
    for (int i = 0; i < 8; ++i) wa[i] = wp[(size_t)i * D];

    // ---- firing preamble from colsum (1 KB read, no staging needed)
    float part = colsum[t] * Sl[n * D + t];
    #pragma unroll
    for (int o = 32; o > 0; o >>= 1) part += __shfl_down(part, o);
    if (lane == 0) sh[w] = part;
    __syncthreads();
    {
        const bool has_input = is_first ? true : (meta_prev[0] > 0.0f);
        const float sdot = (sh[0] + sh[1] + sh[2] + sh[3]) * (1.0f / 16.0f);
        const float tau  = 0.5f * expf(LAMBDA_TAU * (depth - (float)tb[0]));
        const bool fired = (rhol[n] + sdot + boostl[n] >= tau) && has_input;
        if (e0 == 0 && t == 0) fired_cur[n] = fired ? 1.0f : 0.0f;
        if (!fired) return;   // block-uniform: skip staging + W stream
    }

    // ---- stage vin into LDS (16 KB, only fired blocks)
    {
        const float4* s4 = (const float4*)vin_src;
        #pragma unroll
        for (int k = 0; k < 4; ++k)
            ((float4*)vin)[t * 4 + k] = s4[t * 4 + k];
    }
    __syncthreads();

    // ---- main loop: 64 d-rows, ping-pong 8-row W chunks
    const int dbase = w * 64;
    float acc[16];
    #pragma unroll
    for (int b = 0; b < 16; ++b) acc[b] = 0.0f;

    #pragma unroll
    for (int c = 0; c < 8; ++c) {
        float* cur = (c & 1) ? wb : wa;
        float* nxt = (c & 1) ? wa : wb;
        if (c < 7) {
            #pragma unroll
            for (int i = 0; i < 8; ++i)
                nxt[i] = wp[(size_t)((c + 1) * 8 + i) * D];
        }
        #pragma unroll
        for (int i = 0; i < 8; ++i) {
            const float* vr = &vin[(dbase + c * 8 + i) * 16];
            const float4 v0 = *(const float4*)(vr + 0);
            const float4 v1 = *(const float4*)(vr + 4);
            const float4 v2 = *(const float4*)(vr + 8);
            const float4 v3 = *(const float4*)(vr + 12);
            const float wj = cur[i];
            acc[ 0] = fmaf(wj, v0.x, acc[ 0]);
            acc[ 1] = fmaf(wj, v0.y, acc[ 1]);
            acc[ 2] = fmaf(wj, v0.z, acc[ 2]);
            acc[ 3] = fmaf(wj, v0.w, acc[ 3]);
            acc[ 4] = fmaf(wj, v1.x, acc[ 4]);
            acc[ 5] = fmaf(wj, v1.y, acc[ 5]);
            acc[ 6] = fmaf(wj, v1.z, acc[ 6]);
            acc[ 7] = fmaf(wj, v1.w, acc[ 7]);
            acc[ 8] = fmaf(wj, v2.x, acc[ 8]);
            acc[ 9] = fmaf(wj, v2.y, acc[ 9]);
            acc[10] = fmaf(wj, v2.z, acc[10]);
            acc[11] = fmaf(wj, v2.w, acc[11]);
            acc[12] = fmaf(wj, v3.x, acc[12]);
            acc[13] = fmaf(wj, v3.y, acc[13]);
            acc[14] = fmaf(wj, v3.z, acc[14]);
            acc[15] = fmaf(wj, v3.w, acc[15]);
        }
    }

    // ---- cross-wave d-reduce via padded LDS
    {
        float* rr = &red[(w * 64 + lane) * 17];
        #pragma unroll
        for (int b = 0; b < 16; ++b) rr[b] = acc[b];
    }
    __syncthreads();

    // ---- epilogue: thread -> 4 cells (e_loc = t>>2, b = (t&3)*4 + q)
    {
        const int e_loc = t >> 2;
        const int b0    = (t & 3) * 4;
        const float bv  = biasl[n * D + e0 + e_loc];
        float4 o4;
        float s[4];
        #pragma unroll
        for (int q = 0; q < 4; ++q) {
            const int b = b0 + q;
            s[q] = red[(0 * 64 + e_loc) * 17 + b]
                 + red[(1 * 64 + e_loc) * 17 + b]
                 + red[(2 * 64 + e_loc) * 17 + b]
                 + red[(3 * 64 + e_loc) * 17 + b];
        }
        o4.x = tanhf(s[0] + bv);
        o4.y = tanhf(s[1] + bv);
        o4.z = tanhf(s[2] + bv);
        o4.w = tanhf(s[3] + bv);
        *(float4*)(slab + (size_t)n * 4096 + (size_t)(e0 + e_loc) * 16 + b0) = o4;
    }
}

// 64 blocks x 256 thr. Block covers 64 cells (= 4 d-rows); thread=(cell, n-chunk).
// acct[c] = (decay/max(cnt,1)) * sum_n fired[n]*slab[n][c]
// colsum[d] = sum_b acct[d*16+b];  meta[0] = cnt.
__global__ __launch_bounds__(256) void reduce_mid(
    const float* __restrict__ slab, const float* __restrict__ fired_l,
    float* __restrict__ acct, float* __restrict__ colsum,
    float* __restrict__ meta)
{
    __shared__ float part[256];
    __shared__ float shcnt;
    const int t    = threadIdx.x;
    const int cell = blockIdx.x * 64 + (t & 63);
    const int n0   = (t >> 6) * 32;

    float s = 0.0f;
    #pragma unroll 8
    for (int k = 0; k < 32; ++k)
        s = fmaf(fired_l[n0 + k], slab[(size_t)(n0 + k) * 4096 + cell], s);
    part[t] = s;

    if (t < 64) {             // wave 0: fired count
        float c = fired_l[t] + fired_l[t + 64];
        #pragma unroll
        for (int o = 32; o > 0; o >>= 1) c += __shfl_down(c, o);
        if (t == 0) shcnt = c;
    }
    __syncthreads();

    if (t < 64) {
        const float cnt   = shcnt;
        const float scale = expf(-LAMBDA_ASYNC) / fmaxf(cnt, 1.0f);
        float v = (part[t] + part[64 + t] + part[128 + t] + part[192 + t]) * scale;
        acct[blockIdx.x * 64 + t] = v;
        // colsum over the 16 b's of each d (16 consecutive lanes share d)
        float cs = v;
        cs += __shfl_down(cs, 8);
        cs += __shfl_down(cs, 4);
        cs += __shfl_down(cs, 2);
        cs += __shfl_down(cs, 1);
        if ((t & 15) == 0) colsum[(blockIdx.x * 64 + t) >> 4] = cs;
        if (blockIdx.x == 0 && t == 0) meta[0] = cnt;
    }
}

// Final: out[b][e] = sum_n fired[n]*slab[n][e*16+b] / max(cnt,1)
__global__ __launch_bounds__(256) void reduce_final(
    const float* __restrict__ slab, const float* __restrict__ fired_l,
    float* __restrict__ out)
{
    __shared__ float part[256];
    __shared__ float shcnt;
    const int t    = threadIdx.x;
    const int cell = blockIdx.x * 64 + (t & 63);
    const int n0   = (t >> 6) * 32;

    float s = 0.0f;
    #pragma unroll 8
    for (int k = 0; k < 32; ++k)
        s = fmaf(fired_l[n0 + k], slab[(size_t)(n0 + k) * 4096 + cell], s);
    part[t] = s;

    if (t < 64) {
        float c = fired_l[t] + fired_l[t + 64];
        #pragma unroll
        for (int o = 32; o > 0; o >>= 1) c += __shfl_down(c, o);
        if (t == 0) shcnt = c;
    }
    __syncthreads();

    if (t < 64) {
        const float inv = 1.0f / fmaxf(shcnt, 1.0f);
        const int c = blockIdx.x * 64 + t;
        const float v = (part[t] + part[64 + t] + part[128 + t] + part[192 + t]) * inv;
        const int e = c >> 4, b = c & 15;
        out[b * 256 + e] = v;
    }
}

extern "C" void kernel_launch(void* const* d_in, const int* in_sizes, int n_in,
                              void* d_out, int out_size, void* d_ws, size_t ws_size,
                              hipStream_t stream)
{
    const float* X     = (const float*)d_in[0];
    const float* W     = (const float*)d_in[1];
    const float* bias  = (const float*)d_in[2];
    const float* S     = (const float*)d_in[3];
    const float* rho   = (const float*)d_in[4];
    const float* boost = (const float*)d_in[5];
    const int*   tb    = (const int*)d_in[6];
    float* out = (float*)d_out;
    float* ws  = (float*)d_ws;

    float* acct   = ws;
    float* colsum = ws + OFF_COLSUM;
    float* meta   = ws + OFF_META;
    float* fired  = ws + OFF_FIRED;
    float* slab   = ws + OFF_SLAB;

    // xt reuses acct slot (layer 0 stages from it before reduce 0 overwrites)
    transpose_kernel<<<dim3(1), dim3(256), 0, stream>>>(X, acct, colsum);

    for (int l = 0; l < L; ++l) {
        layer_kernel<<<dim3(512), dim3(256), 0, stream>>>(
            W + (size_t)l * N * D * D,
            bias + (size_t)l * N * D,
            S + (size_t)l * N * D,
            rho + (size_t)l * N,
            boost + (size_t)l * N,
            tb,
            acct,            // vin_src: xt for l==0, acct thereafter (serial reuse)
            colsum,
            (l == 0) ? (const float*)nullptr : meta,
            slab,
            fired,
            (float)(l + 1), (l == 0) ? 1 : 0);
        if (l < L - 1) {
            reduce_mid<<<dim3(64), dim3(256), 0, stream>>>(
                slab, fired, acct, colsum, meta);
        } else {
            reduce_final<<<dim3(64), dim3(256), 0, stream>>>(
                slab, fired, out);
        }
    }
}